// Round 1
// baseline (563.547 us; speedup 1.0000x reference)
//
#include <hip/hip_runtime.h>

// GCNWithJK on MI355X.
// Layers collapse to one GEMM each: W_eff = 0.95*W + 0.05*Wr (linearity of Agg).
// Pipeline per call: CSR build -> 3x(GEMM + pull-aggregate) -> fused pool/MLP/log_softmax.

#define FEAT 128

__device__ __forceinline__ int lower_bound_i(const int* a, int n, int key) {
  int lo = 0, hi = n;
  while (lo < hi) { int mid = (lo + hi) >> 1; if (a[mid] < key) lo = mid + 1; else hi = mid; }
  return lo;
}

// ---- weight prep: blend + transpose (Wt[c][k] = 0.95*W[k][c] + 0.05*Wr[k][c]) ----
__global__ void prep_weights(const float* __restrict__ w1, const float* __restrict__ wr1,
                             const float* __restrict__ b1, const float* __restrict__ br1,
                             const float* __restrict__ w2, const float* __restrict__ b2,
                             const float* __restrict__ w3, const float* __restrict__ b3,
                             const float* __restrict__ wr, const float* __restrict__ br,
                             float* __restrict__ Wt, float* __restrict__ beff) {
  __shared__ float tile[128][129];  // +1 pad: transpose read stride breaks bank conflicts
  int l = blockIdx.x;
  const float* W  = (l == 0) ? w1 : ((l == 1) ? w2 : w3);
  const float* Wr = (l == 0) ? wr1 : wr;
  const float* B  = (l == 0) ? b1 : ((l == 1) ? b2 : b3);
  const float* Br = (l == 0) ? br1 : br;
  int t = threadIdx.x;
  for (int idx = t; idx < 128 * 128; idx += 256) {
    int k = idx >> 7, c = idx & 127;
    tile[k][c] = 0.95f * W[idx] + 0.05f * Wr[idx];
  }
  __syncthreads();
  float* out = Wt + l * 128 * 128;
  for (int idx = t; idx < 128 * 128; idx += 256) {
    int c = idx >> 7, k = idx & 127;
    out[idx] = tile[k][c];
  }
  if (t < 128) beff[l * 128 + t] = 0.95f * B[t] + 0.05f * Br[t];
}

// ---- CSR build ----
__global__ void count_edges(const int* __restrict__ row, int E, int* __restrict__ cnt) {
  int e = blockIdx.x * blockDim.x + threadIdx.x;
  if (e < E) atomicAdd(&cnt[row[e]], 1);
}

__global__ void scan1(const int* __restrict__ cnt, int n, int* __restrict__ bsum) {
  __shared__ int sdata[1024];
  int i = blockIdx.x * 1024 + threadIdx.x;
  sdata[threadIdx.x] = (i < n) ? cnt[i] : 0;
  __syncthreads();
  for (int s = 512; s > 0; s >>= 1) {
    if (threadIdx.x < s) sdata[threadIdx.x] += sdata[threadIdx.x + s];
    __syncthreads();
  }
  if (threadIdx.x == 0) bsum[blockIdx.x] = sdata[0];
}

__global__ void scan2(int* __restrict__ bsum, int nb, int* __restrict__ start, int n) {
  if (threadIdx.x == 0 && blockIdx.x == 0) {
    int acc = 0;
    for (int b = 0; b < nb; b++) { int v = bsum[b]; bsum[b] = acc; acc += v; }
    start[n] = acc;
  }
}

__global__ void scan3(const int* __restrict__ cnt, int n, const int* __restrict__ bsum,
                      int* __restrict__ start) {
  __shared__ int sdata[1024];
  int tid = threadIdx.x;
  int i = blockIdx.x * 1024 + tid;
  int v = (i < n) ? cnt[i] : 0;
  sdata[tid] = v;
  __syncthreads();
  for (int off = 1; off < 1024; off <<= 1) {
    int add = (tid >= off) ? sdata[tid - off] : 0;
    __syncthreads();
    sdata[tid] += add;
    __syncthreads();
  }
  if (i < n) start[i] = bsum[blockIdx.x] + sdata[tid] - v;  // exclusive
}

__global__ void fill_edges(const int* __restrict__ edge, int E, const int* __restrict__ start,
                           int* __restrict__ fillcnt, int* __restrict__ cols) {
  int e = blockIdx.x * blockDim.x + threadIdx.x;
  if (e < E) {
    int r = edge[e];
    int p = atomicAdd(&fillcnt[r], 1);
    cols[start[r] + p] = edge[E + e];
  }
}

__global__ void compute_dinv(const int* __restrict__ cnt, int n, float* __restrict__ dinv) {
  int i = blockIdx.x * blockDim.x + threadIdx.x;
  if (i < n) dinv[i] = rsqrtf((float)cnt[i] + 1.0f);  // +1 self-loop; deg>0 always
}

// ---- GEMM: out[r][c] = sum_k X[r][k] * Wt[c][k]; 64x64 tile, 4x4 per thread ----
// LDS XOR-swizzle: byte ^= (row&7)<<4 spreads stride-512B rows over 8 16B slots (<=2-way, free).
__global__ __launch_bounds__(256, 2) void gemm64(const float* __restrict__ X,
                                                 const float* __restrict__ Wt,
                                                 float* __restrict__ out, int n) {
  __shared__ float Xs[64 * 128];
  __shared__ float Ws[64 * 128];
  int R0 = blockIdx.x * 64;
  int C0 = blockIdx.y * 64;
  int t = threadIdx.x;

  #pragma unroll
  for (int it = 0; it < 8; it++) {
    int idx = t + it * 256;          // 0..2047
    int row = idx >> 5, k4 = idx & 31;
    float4 v = make_float4(0.f, 0.f, 0.f, 0.f);
    int gr = R0 + row;
    if (gr < n) v = *(const float4*)(X + gr * FEAT + k4 * 4);
    int byte = ((row << 9) + (k4 << 4)) ^ ((row & 7) << 4);
    *(float4*)((char*)Xs + byte) = v;
  }
  #pragma unroll
  for (int it = 0; it < 8; it++) {
    int idx = t + it * 256;
    int row = idx >> 5, k4 = idx & 31;   // row = local col
    float4 v = *(const float4*)(Wt + (C0 + row) * FEAT + k4 * 4);
    int byte = ((row << 9) + (k4 << 4)) ^ ((row & 7) << 4);
    *(float4*)((char*)Ws + byte) = v;
  }
  __syncthreads();

  int tr = t >> 4, tc = t & 15;
  float acc[4][4];
  #pragma unroll
  for (int i = 0; i < 4; i++)
    #pragma unroll
    for (int j = 0; j < 4; j++) acc[i][j] = 0.f;

  for (int k4 = 0; k4 < 32; k4++) {
    float4 xv[4], wv[4];
    #pragma unroll
    for (int i = 0; i < 4; i++) {
      int row = tr + 16 * i;
      xv[i] = *(const float4*)((const char*)Xs + (((row << 9) + (k4 << 4)) ^ ((row & 7) << 4)));
    }
    #pragma unroll
    for (int j = 0; j < 4; j++) {
      int cl = tc + 16 * j;
      wv[j] = *(const float4*)((const char*)Ws + (((cl << 9) + (k4 << 4)) ^ ((cl & 7) << 4)));
    }
    #pragma unroll
    for (int i = 0; i < 4; i++)
      #pragma unroll
      for (int j = 0; j < 4; j++)
        acc[i][j] += xv[i].x * wv[j].x + xv[i].y * wv[j].y + xv[i].z * wv[j].z + xv[i].w * wv[j].w;
  }

  #pragma unroll
  for (int i = 0; i < 4; i++) {
    int gr = R0 + tr + 16 * i;
    if (gr < n) {
      #pragma unroll
      for (int j = 0; j < 4; j++) out[gr * FEAT + C0 + tc + 16 * j] = acc[i][j];
    }
  }
}

// ---- pull aggregation: one wave per node; h[i] = relu(sum_e xw[col]*norm + self + beff) ----
__global__ void aggregate(const float* __restrict__ xw, const int* __restrict__ cols,
                          const int* __restrict__ start, const float* __restrict__ dinv,
                          const float* __restrict__ beff, float* __restrict__ h, int n) {
  int wave = (blockIdx.x * blockDim.x + threadIdx.x) >> 6;
  int lane = threadIdx.x & 63;
  if (wave >= n) return;
  int i = wave;
  float di = dinv[i];
  float2 v = *(const float2*)(xw + i * FEAT + lane * 2);
  float wii = di * di;
  float a0 = v.x * wii, a1 = v.y * wii;
  int s = start[i], e = start[i + 1];
  for (int idx = s; idx < e; idx++) {
    int c = cols[idx];
    float wc = di * dinv[c];
    float2 u = *(const float2*)(xw + c * FEAT + lane * 2);
    a0 += u.x * wc; a1 += u.y * wc;
  }
  float2 b = *(const float2*)(beff + lane * 2);
  a0 = fmaxf(a0 + b.x, 0.f);
  a1 = fmaxf(a1 + b.y, 0.f);
  *(float2*)(h + i * FEAT + lane * 2) = make_float2(a0, a1);
}

// ---- fused mean-pool (binary search on sorted batch) + lin1 + relu + lin2 + log_softmax ----
__global__ void pool_mlp(const float* __restrict__ h1, const float* __restrict__ h2,
                         const float* __restrict__ h3, const int* __restrict__ batch, int n,
                         const float* __restrict__ lin1w, const float* __restrict__ lin1b,
                         const float* __restrict__ lin2w, const float* __restrict__ lin2b,
                         float* __restrict__ out) {
  __shared__ float mean[384];
  __shared__ float tvec[128];
  __shared__ float logits[10];
  __shared__ float red[2];
  int g = blockIdx.x;
  int t = threadIdx.x;  // 128 threads
  int lo = lower_bound_i(batch, n, g);
  int hi = lower_bound_i(batch, n, g + 1);
  float s1 = 0.f, s2 = 0.f, s3 = 0.f;
  for (int i = lo; i < hi; i++) {
    s1 += h1[i * FEAT + t];
    s2 += h2[i * FEAT + t];
    s3 += h3[i * FEAT + t];
  }
  float invc = 1.0f / fmaxf((float)(hi - lo), 1.0f);
  mean[t] = s1 * invc; mean[128 + t] = s2 * invc; mean[256 + t] = s3 * invc;
  __syncthreads();
  float acc = lin1b[t];
  for (int k = 0; k < 384; k++) acc += mean[k] * lin1w[k * 128 + t];
  tvec[t] = fmaxf(acc, 0.f);
  __syncthreads();
  if (t < 10) {
    float a = lin2b[t];
    for (int k = 0; k < 128; k++) a += tvec[k] * lin2w[k * 10 + t];
    logits[t] = a;
  }
  __syncthreads();
  if (t == 0) {
    float m = -1e30f;
    for (int j = 0; j < 10; j++) m = fmaxf(m, logits[j]);
    float se = 0.f;
    for (int j = 0; j < 10; j++) se += expf(logits[j] - m);
    red[0] = m; red[1] = logf(se);
  }
  __syncthreads();
  if (t < 10) out[g * 10 + t] = logits[t] - red[0] - red[1];
}

extern "C" void kernel_launch(void* const* d_in, const int* in_sizes, int n_in,
                              void* d_out, int out_size, void* d_ws, size_t ws_size,
                              hipStream_t stream) {
  const float* x     = (const float*)d_in[0];
  const int*   edge  = (const int*)d_in[1];   // [2,E] flat: rows then cols
  const int*   batch = (const int*)d_in[2];
  const float* w1    = (const float*)d_in[3];
  const float* b1    = (const float*)d_in[4];
  const float* wr1   = (const float*)d_in[5];
  const float* br1   = (const float*)d_in[6];
  const float* w2    = (const float*)d_in[7];
  const float* b2    = (const float*)d_in[8];
  const float* w3    = (const float*)d_in[9];
  const float* b3    = (const float*)d_in[10];
  const float* wr    = (const float*)d_in[11];
  const float* br    = (const float*)d_in[12];
  const float* lin1w = (const float*)d_in[13];
  const float* lin1b = (const float*)d_in[14];
  const float* lin2w = (const float*)d_in[15];
  const float* lin2b = (const float*)d_in[16];

  int n  = in_sizes[0] / FEAT;   // 50000
  int E  = in_sizes[1] / 2;      // 800000
  int ng = out_size / 10;        // 512

  // workspace carve (256B aligned regions)
  char* p = (char*)d_ws;
  auto carve = [&](size_t bytes) -> void* {
    void* r = (void*)p;
    p += (bytes + 255) & ~(size_t)255;
    return r;
  };
  float* Wt      = (float*)carve(3 * 128 * 128 * sizeof(float));
  float* beff    = (float*)carve(3 * 128 * sizeof(float));
  int*   cnt     = (int*)carve((size_t)n * sizeof(int));
  int*   fillcnt = (int*)carve((size_t)n * sizeof(int));
  int*   start   = (int*)carve((size_t)(n + 1) * sizeof(int));
  int*   bsum    = (int*)carve(64 * sizeof(int));
  int*   cols    = (int*)carve((size_t)E * sizeof(int));
  float* dinv    = (float*)carve((size_t)n * sizeof(float));
  float* xw      = (float*)carve((size_t)n * FEAT * sizeof(float));
  float* h1      = (float*)carve((size_t)n * FEAT * sizeof(float));
  float* h2      = (float*)carve((size_t)n * FEAT * sizeof(float));
  float* h3      = (float*)carve((size_t)n * FEAT * sizeof(float));

  hipMemsetAsync(cnt, 0, (size_t)n * sizeof(int), stream);
  hipMemsetAsync(fillcnt, 0, (size_t)n * sizeof(int), stream);

  prep_weights<<<3, 256, 0, stream>>>(w1, wr1, b1, br1, w2, b2, w3, b3, wr, br, Wt, beff);

  int eb = (E + 255) / 256;
  count_edges<<<eb, 256, 0, stream>>>(edge, E, cnt);
  int nb = (n + 1023) / 1024;
  scan1<<<nb, 1024, 0, stream>>>(cnt, n, bsum);
  scan2<<<1, 64, 0, stream>>>(bsum, nb, start, n);
  scan3<<<nb, 1024, 0, stream>>>(cnt, n, bsum, start);
  fill_edges<<<eb, 256, 0, stream>>>(edge, E, start, fillcnt, cols);
  compute_dinv<<<(n + 255) / 256, 256, 0, stream>>>(cnt, n, dinv);

  dim3 gg((n + 63) / 64, 2);
  int ab = (n * 64 + 255) / 256;

  gemm64<<<gg, 256, 0, stream>>>(x, Wt, xw, n);
  aggregate<<<ab, 256, 0, stream>>>(xw, cols, start, dinv, beff, h1, n);

  gemm64<<<gg, 256, 0, stream>>>(h1, Wt + 128 * 128, xw, n);
  aggregate<<<ab, 256, 0, stream>>>(xw, cols, start, dinv, beff + 128, h2, n);

  gemm64<<<gg, 256, 0, stream>>>(h2, Wt + 2 * 128 * 128, xw, n);
  aggregate<<<ab, 256, 0, stream>>>(xw, cols, start, dinv, beff + 256, h3, n);

  pool_mlp<<<ng, 128, 0, stream>>>(h1, h2, h3, batch, n, lin1w, lin1b, lin2w, lin2b,
                                   (float*)d_out);
}

// Round 3
// 382.747 us; speedup vs baseline: 1.4724x; 1.4724x over previous
//
#include <hip/hip_runtime.h>
#include <hip/hip_fp16.h>

// GCNWithJK on MI355X.
// Layers collapse to one GEMM each: W_eff = 0.95*W + 0.05*Wr (linearity of Agg).
// Pipeline: CSR build -> 3x(GEMM[fp32->fp16 xw] + pull-aggregate[fp16 gather, unroll-4])
//           -> fused pool/MLP/log_softmax.
// fp16 (not bf16) for the gather table: same 2B/elem bandwidth, 8x lower rounding error.

#define FEAT 128

__device__ __forceinline__ int lower_bound_i(const int* a, int n, int key) {
  int lo = 0, hi = n;
  while (lo < hi) { int mid = (lo + hi) >> 1; if (a[mid] < key) lo = mid + 1; else hi = mid; }
  return lo;
}

// ---- weight prep: blend + transpose (Wt[c][k] = 0.95*W[k][c] + 0.05*Wr[k][c]) ----
__global__ void prep_weights(const float* __restrict__ w1, const float* __restrict__ wr1,
                             const float* __restrict__ b1, const float* __restrict__ br1,
                             const float* __restrict__ w2, const float* __restrict__ b2,
                             const float* __restrict__ w3, const float* __restrict__ b3,
                             const float* __restrict__ wr, const float* __restrict__ br,
                             float* __restrict__ Wt, float* __restrict__ beff) {
  __shared__ float tile[128][129];
  int l = blockIdx.x;
  const float* W  = (l == 0) ? w1 : ((l == 1) ? w2 : w3);
  const float* Wr = (l == 0) ? wr1 : wr;
  const float* B  = (l == 0) ? b1 : ((l == 1) ? b2 : b3);
  const float* Br = (l == 0) ? br1 : br;
  int t = threadIdx.x;
  for (int idx = t; idx < 128 * 128; idx += 256) {
    int k = idx >> 7, c = idx & 127;
    tile[k][c] = 0.95f * W[idx] + 0.05f * Wr[idx];
  }
  __syncthreads();
  float* out = Wt + l * 128 * 128;
  for (int idx = t; idx < 128 * 128; idx += 256) {
    int c = idx >> 7, k = idx & 127;
    out[idx] = tile[k][c];
  }
  if (t < 128) beff[l * 128 + t] = 0.95f * B[t] + 0.05f * Br[t];
}

// ---- CSR build ----
__global__ void count_edges(const int* __restrict__ row, int E, int* __restrict__ cnt) {
  int e = blockIdx.x * blockDim.x + threadIdx.x;
  if (e < E) atomicAdd(&cnt[row[e]], 1);
}

__global__ void compute_dinv(const int* __restrict__ cnt, int n, float* __restrict__ dinv) {
  int i = blockIdx.x * blockDim.x + threadIdx.x;
  if (i < n) dinv[i] = rsqrtf((float)cnt[i] + 1.0f);  // +1 self-loop
}

__global__ void scan1(const int* __restrict__ cnt, int n, int* __restrict__ bsum) {
  __shared__ int sdata[1024];
  int i = blockIdx.x * 1024 + threadIdx.x;
  sdata[threadIdx.x] = (i < n) ? cnt[i] : 0;
  __syncthreads();
  for (int s = 512; s > 0; s >>= 1) {
    if (threadIdx.x < s) sdata[threadIdx.x] += sdata[threadIdx.x + s];
    __syncthreads();
  }
  if (threadIdx.x == 0) bsum[blockIdx.x] = sdata[0];
}

__global__ void scan2(int* __restrict__ bsum, int nb, int* __restrict__ start, int n) {
  if (threadIdx.x == 0 && blockIdx.x == 0) {
    int acc = 0;
    for (int b = 0; b < nb; b++) { int v = bsum[b]; bsum[b] = acc; acc += v; }
    start[n] = acc;
  }
}

__global__ void scan3(const int* __restrict__ cnt, int n, const int* __restrict__ bsum,
                      int* __restrict__ start) {
  __shared__ int sdata[1024];
  int tid = threadIdx.x;
  int i = blockIdx.x * 1024 + tid;
  int v = (i < n) ? cnt[i] : 0;
  sdata[tid] = v;
  __syncthreads();
  for (int off = 1; off < 1024; off <<= 1) {
    int add = (tid >= off) ? sdata[tid - off] : 0;
    __syncthreads();
    sdata[tid] += add;
    __syncthreads();
  }
  if (i < n) start[i] = bsum[blockIdx.x] + sdata[tid] - v;  // exclusive
}

__global__ void fill_edges(const int* __restrict__ edge, int E, const int* __restrict__ start,
                           const float* __restrict__ dinv, int* __restrict__ fillcnt,
                           int* __restrict__ cols, float* __restrict__ enorm) {
  int e = blockIdx.x * blockDim.x + threadIdx.x;
  if (e < E) {
    int r = edge[e];
    int c = edge[E + e];
    int p = atomicAdd(&fillcnt[r], 1);
    int pos = start[r] + p;
    cols[pos] = c;
    enorm[pos] = dinv[r] * dinv[c];   // full symmetric norm per edge
  }
}

// ---- GEMM: xwh[r][c] = fp16( sum_k X[r][k] * Wt[c][k] ); 64x64 tile, 4x4/thread ----
__global__ __launch_bounds__(256, 2) void gemm64(const float* __restrict__ X,
                                                 const float* __restrict__ Wt,
                                                 __half* __restrict__ xwh, int n) {
  __shared__ float Xs[64 * 128];
  __shared__ float Ws[64 * 128];
  int R0 = blockIdx.x * 64;
  int C0 = blockIdx.y * 64;
  int t = threadIdx.x;

  #pragma unroll
  for (int it = 0; it < 8; it++) {
    int idx = t + it * 256;
    int row = idx >> 5, k4 = idx & 31;
    float4 v = make_float4(0.f, 0.f, 0.f, 0.f);
    int gr = R0 + row;
    if (gr < n) v = *(const float4*)(X + (size_t)gr * FEAT + k4 * 4);
    int byte = ((row << 9) + (k4 << 4)) ^ ((row & 7) << 4);
    *(float4*)((char*)Xs + byte) = v;
  }
  #pragma unroll
  for (int it = 0; it < 8; it++) {
    int idx = t + it * 256;
    int row = idx >> 5, k4 = idx & 31;
    float4 v = *(const float4*)(Wt + (size_t)(C0 + row) * FEAT + k4 * 4);
    int byte = ((row << 9) + (k4 << 4)) ^ ((row & 7) << 4);
    *(float4*)((char*)Ws + byte) = v;
  }
  __syncthreads();

  int tr = t >> 4, tc = t & 15;
  float acc[4][4];
  #pragma unroll
  for (int i = 0; i < 4; i++)
    #pragma unroll
    for (int j = 0; j < 4; j++) acc[i][j] = 0.f;

  for (int k4 = 0; k4 < 32; k4++) {
    float4 xv[4], wv[4];
    #pragma unroll
    for (int i = 0; i < 4; i++) {
      int row = tr + 16 * i;
      xv[i] = *(const float4*)((const char*)Xs + (((row << 9) + (k4 << 4)) ^ ((row & 7) << 4)));
    }
    #pragma unroll
    for (int j = 0; j < 4; j++) {
      int cl = tc + 16 * j;
      wv[j] = *(const float4*)((const char*)Ws + (((cl << 9) + (k4 << 4)) ^ ((cl & 7) << 4)));
    }
    #pragma unroll
    for (int i = 0; i < 4; i++)
      #pragma unroll
      for (int j = 0; j < 4; j++)
        acc[i][j] += xv[i].x * wv[j].x + xv[i].y * wv[j].y + xv[i].z * wv[j].z + xv[i].w * wv[j].w;
  }

  #pragma unroll
  for (int i = 0; i < 4; i++) {
    int gr = R0 + tr + 16 * i;
    if (gr < n) {
      #pragma unroll
      for (int j = 0; j < 4; j++)
        xwh[(size_t)gr * FEAT + C0 + tc + 16 * j] = __float2half(acc[i][j]);
    }
  }
}

// ---- pull aggregation: one wave/node, fp16 gather, unroll-4 for MLP ----
__global__ __launch_bounds__(256) void aggregate(
    const __half* __restrict__ xwh, const int* __restrict__ cols,
    const float* __restrict__ enorm, const int* __restrict__ start,
    const float* __restrict__ dinv, const float* __restrict__ beff,
    float* __restrict__ h, int n) {
  int wave = (blockIdx.x * blockDim.x + threadIdx.x) >> 6;
  int lane = threadIdx.x & 63;
  if (wave >= n) return;
  float di = dinv[wave];
  float2 sv = __half22float2(*(const __half2*)(xwh + (size_t)wave * FEAT + lane * 2));
  float wii = di * di;
  float a0 = sv.x * wii;
  float a1 = sv.y * wii;
  int s = start[wave], e = start[wave + 1];
  int idx = s;
  for (; idx + 4 <= e; idx += 4) {
    int c0 = cols[idx], c1 = cols[idx + 1], c2 = cols[idx + 2], c3 = cols[idx + 3];
    float w0 = enorm[idx], w1 = enorm[idx + 1], w2 = enorm[idx + 2], w3 = enorm[idx + 3];
    float2 u0 = __half22float2(*(const __half2*)(xwh + (size_t)c0 * FEAT + lane * 2));
    float2 u1 = __half22float2(*(const __half2*)(xwh + (size_t)c1 * FEAT + lane * 2));
    float2 u2 = __half22float2(*(const __half2*)(xwh + (size_t)c2 * FEAT + lane * 2));
    float2 u3 = __half22float2(*(const __half2*)(xwh + (size_t)c3 * FEAT + lane * 2));
    a0 += u0.x * w0 + u1.x * w1 + u2.x * w2 + u3.x * w3;
    a1 += u0.y * w0 + u1.y * w1 + u2.y * w2 + u3.y * w3;
  }
  for (; idx < e; idx++) {
    int c = cols[idx];
    float w = enorm[idx];
    float2 u = __half22float2(*(const __half2*)(xwh + (size_t)c * FEAT + lane * 2));
    a0 += u.x * w;
    a1 += u.y * w;
  }
  float2 b = *(const float2*)(beff + lane * 2);
  a0 = fmaxf(a0 + b.x, 0.f);
  a1 = fmaxf(a1 + b.y, 0.f);
  *(float2*)(h + (size_t)wave * FEAT + lane * 2) = make_float2(a0, a1);
}

// ---- fused mean-pool + lin1 + relu + lin2 + log_softmax (256 threads/block!) ----
__global__ __launch_bounds__(256) void pool_mlp(
    const float* __restrict__ h1, const float* __restrict__ h2,
    const float* __restrict__ h3, const int* __restrict__ batch, int n,
    const float* __restrict__ lin1w, const float* __restrict__ lin1b,
    const float* __restrict__ lin2w, const float* __restrict__ lin2b,
    float* __restrict__ out) {
  __shared__ float part[8][384];
  __shared__ float mean[384];
  __shared__ float tvec[128];
  __shared__ float logits[10];
  __shared__ float red[2];
  int g = blockIdx.x;
  int t = threadIdx.x;   // 256 threads
  int lo = lower_bound_i(batch, n, g);
  int hi = lower_bound_i(batch, n, g + 1);
  int rg = t >> 5, f4 = t & 31;   // 8 row-groups x 32 float4-lanes
  float4 s1 = make_float4(0.f, 0.f, 0.f, 0.f);
  float4 s2 = make_float4(0.f, 0.f, 0.f, 0.f);
  float4 s3 = make_float4(0.f, 0.f, 0.f, 0.f);
  for (int i = lo + rg; i < hi; i += 8) {
    float4 v1 = *((const float4*)(h1 + (size_t)i * FEAT) + f4);
    float4 v2 = *((const float4*)(h2 + (size_t)i * FEAT) + f4);
    float4 v3 = *((const float4*)(h3 + (size_t)i * FEAT) + f4);
    s1.x += v1.x; s1.y += v1.y; s1.z += v1.z; s1.w += v1.w;
    s2.x += v2.x; s2.y += v2.y; s2.z += v2.z; s2.w += v2.w;
    s3.x += v3.x; s3.y += v3.y; s3.z += v3.z; s3.w += v3.w;
  }
  *(float4*)&part[rg][f4 * 4]       = s1;
  *(float4*)&part[rg][128 + f4 * 4] = s2;
  *(float4*)&part[rg][256 + f4 * 4] = s3;
  __syncthreads();
  float invc = 1.0f / fmaxf((float)(hi - lo), 1.0f);
  for (int j = t; j < 384; j += 256) {
    float acc = 0.f;
    #pragma unroll
    for (int r = 0; r < 8; r++) acc += part[r][j];
    mean[j] = acc * invc;
  }
  __syncthreads();
  if (t < 128) {
    float acc = lin1b[t];
    for (int k = 0; k < 384; k++) acc += mean[k] * lin1w[k * 128 + t];
    tvec[t] = fmaxf(acc, 0.f);
  }
  __syncthreads();
  if (t < 10) {
    float a = lin2b[t];
    for (int k = 0; k < 128; k++) a += tvec[k] * lin2w[k * 10 + t];
    logits[t] = a;
  }
  __syncthreads();
  if (t == 0) {
    float m = -1e30f;
    for (int j = 0; j < 10; j++) m = fmaxf(m, logits[j]);
    float se = 0.f;
    for (int j = 0; j < 10; j++) se += expf(logits[j] - m);
    red[0] = m; red[1] = logf(se);
  }
  __syncthreads();
  if (t < 10) out[g * 10 + t] = logits[t] - red[0] - red[1];
}

extern "C" void kernel_launch(void* const* d_in, const int* in_sizes, int n_in,
                              void* d_out, int out_size, void* d_ws, size_t ws_size,
                              hipStream_t stream) {
  const float* x     = (const float*)d_in[0];
  const int*   edge  = (const int*)d_in[1];
  const int*   batch = (const int*)d_in[2];
  const float* w1    = (const float*)d_in[3];
  const float* b1    = (const float*)d_in[4];
  const float* wr1   = (const float*)d_in[5];
  const float* br1   = (const float*)d_in[6];
  const float* w2    = (const float*)d_in[7];
  const float* b2    = (const float*)d_in[8];
  const float* w3    = (const float*)d_in[9];
  const float* b3    = (const float*)d_in[10];
  const float* wr    = (const float*)d_in[11];
  const float* br    = (const float*)d_in[12];
  const float* lin1w = (const float*)d_in[13];
  const float* lin1b = (const float*)d_in[14];
  const float* lin2w = (const float*)d_in[15];
  const float* lin2b = (const float*)d_in[16];

  int n  = in_sizes[0] / FEAT;   // 50000
  int E  = in_sizes[1] / 2;      // 800000
  int ng = out_size / 10;        // 512

  char* p = (char*)d_ws;
  auto carve = [&](size_t bytes) -> void* {
    void* r = (void*)p;
    p += (bytes + 255) & ~(size_t)255;
    return r;
  };
  float*  Wt      = (float*)carve(3 * 128 * 128 * sizeof(float));
  float*  beff    = (float*)carve(3 * 128 * sizeof(float));
  int*    cnt     = (int*)carve((size_t)n * sizeof(int));
  int*    fillcnt = (int*)carve((size_t)n * sizeof(int));
  int*    start   = (int*)carve((size_t)(n + 1) * sizeof(int));
  int*    bsum    = (int*)carve(64 * sizeof(int));
  int*    cols    = (int*)carve((size_t)E * sizeof(int));
  float*  enorm   = (float*)carve((size_t)E * sizeof(float));
  float*  dinv    = (float*)carve((size_t)n * sizeof(float));
  __half* xwh     = (__half*)carve((size_t)n * FEAT * sizeof(__half));
  float*  h1      = (float*)carve((size_t)n * FEAT * sizeof(float));
  float*  h2      = (float*)carve((size_t)n * FEAT * sizeof(float));
  float*  h3      = (float*)carve((size_t)n * FEAT * sizeof(float));

  hipMemsetAsync(cnt, 0, (size_t)n * sizeof(int), stream);
  hipMemsetAsync(fillcnt, 0, (size_t)n * sizeof(int), stream);

  prep_weights<<<3, 256, 0, stream>>>(w1, wr1, b1, br1, w2, b2, w3, b3, wr, br, Wt, beff);

  int eb = (E + 255) / 256;
  count_edges<<<eb, 256, 0, stream>>>(edge, E, cnt);
  compute_dinv<<<(n + 255) / 256, 256, 0, stream>>>(cnt, n, dinv);
  int nb = (n + 1023) / 1024;
  scan1<<<nb, 1024, 0, stream>>>(cnt, n, bsum);
  scan2<<<1, 64, 0, stream>>>(bsum, nb, start, n);
  scan3<<<nb, 1024, 0, stream>>>(cnt, n, bsum, start);
  fill_edges<<<eb, 256, 0, stream>>>(edge, E, start, dinv, fillcnt, cols, enorm);

  dim3 gg((n + 63) / 64, 2);
  int ab = (n * 64 + 255) / 256;

  gemm64<<<gg, 256, 0, stream>>>(x, Wt, xwh, n);
  aggregate<<<ab, 256, 0, stream>>>(xwh, cols, enorm, start, dinv, beff, h1, n);

  gemm64<<<gg, 256, 0, stream>>>(h1, Wt + 128 * 128, xwh, n);
  aggregate<<<ab, 256, 0, stream>>>(xwh, cols, enorm, start, dinv, beff + 128, h2, n);

  gemm64<<<gg, 256, 0, stream>>>(h2, Wt + 2 * 128 * 128, xwh, n);
  aggregate<<<ab, 256, 0, stream>>>(xwh, cols, enorm, start, dinv, beff + 256, h3, n);

  pool_mlp<<<ng, 256, 0, stream>>>(h1, h2, h3, batch, n, lin1w, lin1b, lin2w, lin2b,
                                   (float*)d_out);
}

// Round 4
// 286.363 us; speedup vs baseline: 1.9679x; 1.3366x over previous
//
#include <hip/hip_runtime.h>
#include <hip/hip_fp16.h>

// GCNWithJK on MI355X.
// Layers collapse to one GEMM each: W_eff = 0.95*W + 0.05*Wr (linearity of Agg).
// All activations fp16 (threshold 4.8e-2 leaves ~50x margin): GEMMs use
// v_mfma_f32_16x16x32_f16 with fp32 accumulate; gathers + pools read fp16.
// Pipeline: f32->f16 x | CSR build -> 3x(MFMA-GEMM + pull-aggregate) -> pool/MLP.

#define FEAT 128

typedef _Float16 half8 __attribute__((ext_vector_type(8)));
typedef _Float16 half4 __attribute__((ext_vector_type(4)));
typedef float f32x4 __attribute__((ext_vector_type(4)));

__device__ __forceinline__ int lower_bound_i(const int* a, int n, int key) {
  int lo = 0, hi = n;
  while (lo < hi) { int mid = (lo + hi) >> 1; if (a[mid] < key) lo = mid + 1; else hi = mid; }
  return lo;
}

// ---- x fp32 -> fp16 ----
__global__ void f2h(const float* __restrict__ in, __half* __restrict__ out, int n4) {
  int i = blockIdx.x * blockDim.x + threadIdx.x;
  if (i < n4) {
    float4 v = *((const float4*)in + i);
    half4 h = { (_Float16)v.x, (_Float16)v.y, (_Float16)v.z, (_Float16)v.w };
    *((half4*)out + i) = h;
  }
}

// ---- weight prep: blend + transpose -> fp16 (Wt[c][k] = 0.95*W[k][c]+0.05*Wr[k][c]) ----
__global__ void prep_weights(const float* __restrict__ w1, const float* __restrict__ wr1,
                             const float* __restrict__ b1, const float* __restrict__ br1,
                             const float* __restrict__ w2, const float* __restrict__ b2,
                             const float* __restrict__ w3, const float* __restrict__ b3,
                             const float* __restrict__ wr, const float* __restrict__ br,
                             __half* __restrict__ Wt, float* __restrict__ beff) {
  __shared__ float tile[128][129];
  int l = blockIdx.x;
  const float* W  = (l == 0) ? w1 : ((l == 1) ? w2 : w3);
  const float* Wr = (l == 0) ? wr1 : wr;
  const float* B  = (l == 0) ? b1 : ((l == 1) ? b2 : b3);
  const float* Br = (l == 0) ? br1 : br;
  int t = threadIdx.x;
  for (int idx = t; idx < 128 * 128; idx += 256) {
    int k = idx >> 7, c = idx & 127;
    tile[k][c] = 0.95f * W[idx] + 0.05f * Wr[idx];
  }
  __syncthreads();
  __half* out = Wt + l * 128 * 128;
  for (int idx = t; idx < 128 * 128; idx += 256) {
    int c = idx >> 7, k = idx & 127;
    out[idx] = __float2half(tile[k][c]);
  }
  if (t < 128) beff[l * 128 + t] = 0.95f * B[t] + 0.05f * Br[t];
}

// ---- CSR build ----
__global__ void count_edges(const int* __restrict__ row, int E, int* __restrict__ cnt) {
  int e = blockIdx.x * blockDim.x + threadIdx.x;
  if (e < E) atomicAdd(&cnt[row[e]], 1);
}

__global__ void compute_dinv(const int* __restrict__ cnt, int n, float* __restrict__ dinv) {
  int i = blockIdx.x * blockDim.x + threadIdx.x;
  if (i < n) dinv[i] = rsqrtf((float)cnt[i] + 1.0f);  // +1 self-loop
}

__global__ void scan1(const int* __restrict__ cnt, int n, int* __restrict__ bsum) {
  __shared__ int sdata[1024];
  int i = blockIdx.x * 1024 + threadIdx.x;
  sdata[threadIdx.x] = (i < n) ? cnt[i] : 0;
  __syncthreads();
  for (int s = 512; s > 0; s >>= 1) {
    if (threadIdx.x < s) sdata[threadIdx.x] += sdata[threadIdx.x + s];
    __syncthreads();
  }
  if (threadIdx.x == 0) bsum[blockIdx.x] = sdata[0];
}

__global__ void scan2(int* __restrict__ bsum, int nb, int* __restrict__ start, int n) {
  if (threadIdx.x == 0 && blockIdx.x == 0) {
    int acc = 0;
    for (int b = 0; b < nb; b++) { int v = bsum[b]; bsum[b] = acc; acc += v; }
    start[n] = acc;
  }
}

__global__ void scan3(const int* __restrict__ cnt, int n, const int* __restrict__ bsum,
                      int* __restrict__ start) {
  __shared__ int sdata[1024];
  int tid = threadIdx.x;
  int i = blockIdx.x * 1024 + tid;
  int v = (i < n) ? cnt[i] : 0;
  sdata[tid] = v;
  __syncthreads();
  for (int off = 1; off < 1024; off <<= 1) {
    int add = (tid >= off) ? sdata[tid - off] : 0;
    __syncthreads();
    sdata[tid] += add;
    __syncthreads();
  }
  if (i < n) start[i] = bsum[blockIdx.x] + sdata[tid] - v;  // exclusive
}

__global__ void fill_edges(const int* __restrict__ edge, int E, const int* __restrict__ start,
                           const float* __restrict__ dinv, int* __restrict__ fillcnt,
                           int* __restrict__ cols, float* __restrict__ enorm) {
  int e = blockIdx.x * blockDim.x + threadIdx.x;
  if (e < E) {
    int r = edge[e];
    int c = edge[E + e];
    int p = atomicAdd(&fillcnt[r], 1);
    int pos = start[r] + p;
    cols[pos] = c;
    enorm[pos] = dinv[r] * dinv[c];
  }
}

// ---- MFMA GEMM: xwh[r][c] = fp16( sum_k Xh[r][k] * Wt[c][k] ) ----
// 4 waves/block, 16-row strip per wave; B (=Wt fp16, 32KB) staged in XOR-swizzled LDS.
// A-frag: lane holds X[row=l&15][k=(l>>4)*8 ..+7]; B-frag: Wt[col=l&15][k=(l>>4)*8 ..+7].
// C/D: col=lane&15, row=(lane>>4)*4+reg (m89-verified layout).
__global__ __launch_bounds__(256) void gemm_mfma(const __half* __restrict__ Xh,
                                                 const __half* __restrict__ Wt,
                                                 __half* __restrict__ xwh, int ntile) {
  __shared__ __half Wlds[128 * 128];
  int t = threadIdx.x;
  #pragma unroll
  for (int it = 0; it < 8; it++) {
    int idx = t + it * 256;          // 2048 chunks of 16B
    int c = idx >> 4, ch = idx & 15;
    float4 v = *((const float4*)Wt + idx);
    int byte = ((c << 8) + (ch << 4)) ^ ((c & 7) << 4);
    *(float4*)((char*)Wlds + byte) = v;
  }
  __syncthreads();

  int wid = t >> 6, lane = t & 63;
  int tile = blockIdx.x * 4 + wid;
  if (tile >= ntile) return;
  int r = lane & 15, kg = lane >> 4;
  size_t rowbase = (size_t)tile * 16;

  const half8* aptr = (const half8*)(Xh + (rowbase + r) * FEAT + kg * 8);
  half8 a[4];
  #pragma unroll
  for (int ks = 0; ks < 4; ks++) a[ks] = aptr[ks * 4];   // k0 = ks*32 + kg*8

  f32x4 acc[8];
  #pragma unroll
  for (int nt = 0; nt < 8; nt++) acc[nt] = (f32x4){0.f, 0.f, 0.f, 0.f};

  #pragma unroll
  for (int nt = 0; nt < 8; nt++) {
    #pragma unroll
    for (int ks = 0; ks < 4; ks++) {
      int byte = ((((nt << 4) + r) << 8) + (ks << 6) + (kg << 4)) ^ ((r & 7) << 4);
      half8 b = *(const half8*)((const char*)Wlds + byte);
      acc[nt] = __builtin_amdgcn_mfma_f32_16x16x32_f16(a[ks], b, acc[nt], 0, 0, 0);
    }
  }

  int orow = kg * 4;
  #pragma unroll
  for (int nt = 0; nt < 8; nt++)
    #pragma unroll
    for (int j = 0; j < 4; j++)
      xwh[(rowbase + orow + j) * FEAT + (nt << 4) + r] = __float2half(acc[nt][j]);
}

// ---- pull aggregation: one wave/node, fp16 gather, unroll-8 for MLP; fp16 output ----
__global__ __launch_bounds__(256) void aggregate(
    const __half* __restrict__ xwh, const int* __restrict__ cols,
    const float* __restrict__ enorm, const int* __restrict__ start,
    const float* __restrict__ dinv, const float* __restrict__ beff,
    __half* __restrict__ h, int n) {
  int wave = (blockIdx.x * blockDim.x + threadIdx.x) >> 6;
  int lane = threadIdx.x & 63;
  if (wave >= n) return;
  float di = dinv[wave];
  float2 sv = __half22float2(*(const __half2*)(xwh + (size_t)wave * FEAT + lane * 2));
  float wii = di * di;
  float a0 = sv.x * wii;
  float a1 = sv.y * wii;
  int s = start[wave], e = start[wave + 1];
  int idx = s;
  for (; idx + 8 <= e; idx += 8) {
    int c[8]; float w[8]; float2 u[8];
    #pragma unroll
    for (int q = 0; q < 8; q++) { c[q] = cols[idx + q]; w[q] = enorm[idx + q]; }
    #pragma unroll
    for (int q = 0; q < 8; q++)
      u[q] = __half22float2(*(const __half2*)(xwh + (size_t)c[q] * FEAT + lane * 2));
    #pragma unroll
    for (int q = 0; q < 8; q++) { a0 += u[q].x * w[q]; a1 += u[q].y * w[q]; }
  }
  for (; idx + 4 <= e; idx += 4) {
    int c[4]; float w[4]; float2 u[4];
    #pragma unroll
    for (int q = 0; q < 4; q++) { c[q] = cols[idx + q]; w[q] = enorm[idx + q]; }
    #pragma unroll
    for (int q = 0; q < 4; q++)
      u[q] = __half22float2(*(const __half2*)(xwh + (size_t)c[q] * FEAT + lane * 2));
    #pragma unroll
    for (int q = 0; q < 4; q++) { a0 += u[q].x * w[q]; a1 += u[q].y * w[q]; }
  }
  for (; idx < e; idx++) {
    int c = cols[idx];
    float w = enorm[idx];
    float2 u = __half22float2(*(const __half2*)(xwh + (size_t)c * FEAT + lane * 2));
    a0 += u.x * w;
    a1 += u.y * w;
  }
  float2 b = *(const float2*)(beff + lane * 2);
  a0 = fmaxf(a0 + b.x, 0.f);
  a1 = fmaxf(a1 + b.y, 0.f);
  *(__half2*)(h + (size_t)wave * FEAT + lane * 2) = __float22half2_rn(make_float2(a0, a1));
}

// ---- fused mean-pool + lin1 + relu + lin2 + log_softmax (256 threads) ----
__global__ __launch_bounds__(256) void pool_mlp(
    const __half* __restrict__ h1, const __half* __restrict__ h2,
    const __half* __restrict__ h3, const int* __restrict__ batch, int n,
    const float* __restrict__ lin1w, const float* __restrict__ lin1b,
    const float* __restrict__ lin2w, const float* __restrict__ lin2b,
    float* __restrict__ out) {
  __shared__ float part[8][384];
  __shared__ float mean[384];
  __shared__ float tvec[128];
  __shared__ float logits[10];
  __shared__ float red[2];
  int g = blockIdx.x;
  int t = threadIdx.x;   // 256 threads
  int lo = lower_bound_i(batch, n, g);
  int hi = lower_bound_i(batch, n, g + 1);
  int rg = t >> 5, f4 = t & 31;   // 8 row-groups x 32 lanes (4 halves each)
  float s1[4] = {0,0,0,0}, s2[4] = {0,0,0,0}, s3[4] = {0,0,0,0};
  for (int i = lo + rg; i < hi; i += 8) {
    half4 v1 = *((const half4*)(h1 + (size_t)i * FEAT) + f4);
    half4 v2 = *((const half4*)(h2 + (size_t)i * FEAT) + f4);
    half4 v3 = *((const half4*)(h3 + (size_t)i * FEAT) + f4);
    #pragma unroll
    for (int q = 0; q < 4; q++) {
      s1[q] += (float)v1[q]; s2[q] += (float)v2[q]; s3[q] += (float)v3[q];
    }
  }
  #pragma unroll
  for (int q = 0; q < 4; q++) {
    part[rg][f4 * 4 + q]       = s1[q];
    part[rg][128 + f4 * 4 + q] = s2[q];
    part[rg][256 + f4 * 4 + q] = s3[q];
  }
  __syncthreads();
  float invc = 1.0f / fmaxf((float)(hi - lo), 1.0f);
  for (int j = t; j < 384; j += 256) {
    float acc = 0.f;
    #pragma unroll
    for (int r = 0; r < 8; r++) acc += part[r][j];
    mean[j] = acc * invc;
  }
  __syncthreads();
  if (t < 128) {
    float acc = lin1b[t];
    for (int k = 0; k < 384; k++) acc += mean[k] * lin1w[k * 128 + t];
    tvec[t] = fmaxf(acc, 0.f);
  }
  __syncthreads();
  if (t < 10) {
    float a = lin2b[t];
    for (int k = 0; k < 128; k++) a += tvec[k] * lin2w[k * 10 + t];
    logits[t] = a;
  }
  __syncthreads();
  if (t == 0) {
    float m = -1e30f;
    for (int j = 0; j < 10; j++) m = fmaxf(m, logits[j]);
    float se = 0.f;
    for (int j = 0; j < 10; j++) se += expf(logits[j] - m);
    red[0] = m; red[1] = logf(se);
  }
  __syncthreads();
  if (t < 10) out[g * 10 + t] = logits[t] - red[0] - red[1];
}

extern "C" void kernel_launch(void* const* d_in, const int* in_sizes, int n_in,
                              void* d_out, int out_size, void* d_ws, size_t ws_size,
                              hipStream_t stream) {
  const float* x     = (const float*)d_in[0];
  const int*   edge  = (const int*)d_in[1];
  const int*   batch = (const int*)d_in[2];
  const float* w1    = (const float*)d_in[3];
  const float* b1    = (const float*)d_in[4];
  const float* wr1   = (const float*)d_in[5];
  const float* br1   = (const float*)d_in[6];
  const float* w2    = (const float*)d_in[7];
  const float* b2    = (const float*)d_in[8];
  const float* w3    = (const float*)d_in[9];
  const float* b3    = (const float*)d_in[10];
  const float* wr    = (const float*)d_in[11];
  const float* br    = (const float*)d_in[12];
  const float* lin1w = (const float*)d_in[13];
  const float* lin1b = (const float*)d_in[14];
  const float* lin2w = (const float*)d_in[15];
  const float* lin2b = (const float*)d_in[16];

  int n  = in_sizes[0] / FEAT;   // 50000
  int E  = in_sizes[1] / 2;      // 800000
  int ng = out_size / 10;        // 512

  char* p = (char*)d_ws;
  auto carve = [&](size_t bytes) -> void* {
    void* r = (void*)p;
    p += (bytes + 255) & ~(size_t)255;
    return r;
  };
  __half* Wt      = (__half*)carve(3 * 128 * 128 * sizeof(__half));
  float*  beff    = (float*)carve(3 * 128 * sizeof(float));
  int*    cnt     = (int*)carve((size_t)n * sizeof(int));
  int*    fillcnt = (int*)carve((size_t)n * sizeof(int));
  int*    start   = (int*)carve((size_t)(n + 1) * sizeof(int));
  int*    bsum    = (int*)carve(64 * sizeof(int));
  int*    cols    = (int*)carve((size_t)E * sizeof(int));
  float*  enorm   = (float*)carve((size_t)E * sizeof(float));
  float*  dinv    = (float*)carve((size_t)n * sizeof(float));
  __half* xh      = (__half*)carve((size_t)n * FEAT * sizeof(__half));
  __half* xwh     = (__half*)carve((size_t)n * FEAT * sizeof(__half));
  __half* h1      = (__half*)carve((size_t)n * FEAT * sizeof(__half));
  __half* h2      = (__half*)carve((size_t)n * FEAT * sizeof(__half));
  __half* h3      = (__half*)carve((size_t)n * FEAT * sizeof(__half));

  hipMemsetAsync(cnt, 0, (size_t)n * sizeof(int), stream);
  hipMemsetAsync(fillcnt, 0, (size_t)n * sizeof(int), stream);

  prep_weights<<<3, 256, 0, stream>>>(w1, wr1, b1, br1, w2, b2, w3, b3, wr, br, Wt, beff);

  int n4 = n * FEAT / 4;
  f2h<<<(n4 + 255) / 256, 256, 0, stream>>>(x, xh, n4);

  int eb = (E + 255) / 256;
  count_edges<<<eb, 256, 0, stream>>>(edge, E, cnt);
  compute_dinv<<<(n + 255) / 256, 256, 0, stream>>>(cnt, n, dinv);
  int nb = (n + 1023) / 1024;
  scan1<<<nb, 1024, 0, stream>>>(cnt, n, bsum);
  scan2<<<1, 64, 0, stream>>>(bsum, nb, start, n);
  scan3<<<nb, 1024, 0, stream>>>(cnt, n, bsum, start);
  fill_edges<<<eb, 256, 0, stream>>>(edge, E, start, dinv, fillcnt, cols, enorm);

  int ntile = (n + 15) / 16;            // 3125 (n divisible by 16)
  int gb = (ntile + 3) / 4;             // 4 waves/block
  int ab = (n * 64 + 255) / 256;

  gemm_mfma<<<gb, 256, 0, stream>>>(xh, Wt, xwh, ntile);
  aggregate<<<ab, 256, 0, stream>>>(xwh, cols, enorm, start, dinv, beff, h1, n);

  gemm_mfma<<<gb, 256, 0, stream>>>(h1, Wt + 128 * 128, xwh, ntile);
  aggregate<<<ab, 256, 0, stream>>>(xwh, cols, enorm, start, dinv, beff + 128, h2, n);

  gemm_mfma<<<gb, 256, 0, stream>>>(h2, Wt + 2 * 128 * 128, xwh, ntile);
  aggregate<<<ab, 256, 0, stream>>>(xwh, cols, enorm, start, dinv, beff + 256, h3, n);

  pool_mlp<<<ng, 256, 0, stream>>>(h1, h2, h3, batch, n, lin1w, lin1b, lin2w, lin2b,
                                   (float*)d_out);
}